// Round 13
// baseline (354.384 us; speedup 1.0000x reference)
//
#include <hip/hip_runtime.h>
#include <hip/hip_fp16.h>
#include <math.h>

#define NATOMS 65536

typedef _Float16 f16_t;
typedef __attribute__((ext_vector_type(8))) _Float16 half8;
typedef __attribute__((ext_vector_type(4))) float f32x4;

__constant__ int c_offs[12] = {0,1536,9728,26112,50688,62976,64000,64512,65024,65280,65408,65536};

struct Adj { const int* p[10]; };

__device__ __forceinline__ int seg_of(int row) {
    int s = 0;
#pragma unroll
    for (int i = 1; i <= 10; ++i) s += (row >= c_offs[i]) ? 1 : 0;
    return s;
}

// packed f16 max (exact)
__device__ __forceinline__ half8 max8(half8 a, half8 b) {
    half8 r;
#pragma unroll
    for (int e = 0; e < 8; ++e) r[e] = (a[e] >= b[e]) ? a[e] : b[e];
    return r;
}

// Blob layout (MFMA A-fragment order), NKB = cols/32:
//   addr(r,k) = ((r>>4)*NKB + (k>>5))*512 + ((k>>3)&3)*128 + (r&15)*8 + (k&7)
// Key identity: chunk*512 + lane*8 IS the per-lane MFMA fragment -> blob tensors
// load global->VGPR directly. Row-major fragment: rm[(row16+l16)*LD + kb*32+quad*8].
// All segment boundaries are multiples of 128 -> 128-row tiles are seg-uniform.
// R12 lesson: launch_bounds must NOT squeeze VGPR below the reg-dbuf set
// ((256,4) -> VGPR 64 -> serialized loads -> +8us on gc2). Keep (256,2).

// ---------------- merged: weight packing (+ counts zeroing) + cvt_pad ----------------
__global__ void pack_cvt(const float* __restrict__ g1w0, const float* __restrict__ g1ws,
                         const float* __restrict__ g1wn,
                         const float* __restrict__ g2w0, const float* __restrict__ g2ws,
                         const float* __restrict__ g2wn,
                         const float* __restrict__ dw, const float* __restrict__ ow,
                         f16_t* __restrict__ W1p, f16_t* __restrict__ W2p,
                         f16_t* __restrict__ Wdp, f16_t* __restrict__ Wop,
                         int* __restrict__ counts,
                         const float* __restrict__ xf, f16_t* __restrict__ xq) {
    if (blockIdx.x >= 8384) {
        int idx = (blockIdx.x - 8384) * 256 + threadIdx.x;   // 65536*12 exact
        int r = idx / 12;
        int cc = idx - r * 12;
        int c = cc << 3;
        f16_t o[8];
#pragma unroll
        for (int e = 0; e < 8; ++e)
            o[e] = (c + e < 75) ? (f16_t)xf[(size_t)r*75 + c + e] : (f16_t)0.f;
        *(uint4*)(xq + (size_t)r*96 + c) = *(uint4*)o;
        return;
    }
    int idx = blockIdx.x * 256 + threadIdx.x;   // 8384*256 = 2146304 exact
    if (idx < 2048) counts[idx] = 0;
    if (idx < 540672) {
        int j = idx & 7, lane = (idx >> 3) & 63;
        int kb = (idx >> 9) % 6;
        int rest = idx / (512 * 6);
        int ni = rest & 15, s = rest >> 4;
        int k = kb * 32 + (lane >> 4) * 8 + j;
        int n = ni * 16 + (lane & 15);
        float v = 0.f;
        if (k < 75) v = (s == 0) ? g1w0[k*256 + n] : g1ws[((s-1)*75 + k)*256 + n];
        else if (k >= 96 && k < 171 && s > 0) v = g1wn[((s-1)*75 + (k-96))*256 + n];
        W1p[idx] = (f16_t)v;
    } else if (idx < 1982464) {
        int i2 = idx - 540672;
        int j = i2 & 7, lane = (i2 >> 3) & 63;
        int kb = (i2 >> 9) & 15;
        int rest = i2 >> 13;
        int ni = rest & 15, s = rest >> 4;
        int k = kb * 32 + (lane >> 4) * 8 + j;
        int n = ni * 16 + (lane & 15);
        float v = 0.f;
        if (k < 256) v = (s == 0) ? g2w0[k*256 + n] : g2ws[((s-1)*256 + k)*256 + n];
        else if (s > 0) v = g2wn[((s-1)*256 + (k-256))*256 + n];
        W2p[i2] = (f16_t)v;
    } else if (idx < 2113536) {
        int i2 = idx - 1982464;
        int j = i2 & 7, lane = (i2 >> 3) & 63;
        int kb = (i2 >> 9) & 7;
        int ni = (i2 >> 12) & 31;
        int k = kb * 32 + (lane >> 4) * 8 + j;
        int n = ni * 16 + (lane & 15);
        Wdp[i2] = (f16_t)dw[(size_t)k*512 + n];
    } else {
        int i2 = idx - 2113536;
        int j = i2 & 7, lane = (i2 >> 3) & 63;
        int kb = (i2 >> 9) & 31;
        int ni = i2 >> 14;
        int k = kb * 32 + (lane >> 4) * 8 + j;
        int n = ni * 16 + (lane & 15);
        Wop[i2] = (n < 24) ? (f16_t)ow[k*24 + n] : (f16_t)0.f;
    }
}

// ---------------- compile-time-degree gather helpers (row-major sources) ----------------
template<int D, int LD>
__device__ __forceinline__ void gathD(float* v, const f16_t* __restrict__ src,
                                      const int* __restrict__ ap, int c) {
    int rows[D];
#pragma unroll
    for (int j = 0; j < D; ++j) rows[j] = ap[j];
    uint4 raw[D];
#pragma unroll
    for (int j = 0; j < D; ++j) raw[j] = *(const uint4*)(src + (size_t)rows[j]*LD + c);
#pragma unroll
    for (int j = 0; j < D; ++j) {
        const f16_t* u = (const f16_t*)&raw[j];
#pragma unroll
        for (int e = 0; e < 8; ++e) v[e] += (float)u[e];
    }
}

template<int LD>
__device__ __forceinline__ void gath_sum(float* v, const f16_t* __restrict__ src,
                                         const int* __restrict__ ap, int s, int c) {
    switch (s) {
        case 1:  gathD<1,LD>(v,src,ap,c);  break;
        case 2:  gathD<2,LD>(v,src,ap,c);  break;
        case 3:  gathD<3,LD>(v,src,ap,c);  break;
        case 4:  gathD<4,LD>(v,src,ap,c);  break;
        case 5:  gathD<5,LD>(v,src,ap,c);  break;
        case 6:  gathD<6,LD>(v,src,ap,c);  break;
        case 7:  gathD<7,LD>(v,src,ap,c);  break;
        case 8:  gathD<8,LD>(v,src,ap,c);  break;
        case 9:  gathD<9,LD>(v,src,ap,c);  break;
        case 10: gathD<10,LD>(v,src,ap,c); break;
        default: break;
    }
}

template<int D, int LD>
__device__ __forceinline__ void gathD_pk(half8& v, const f16_t* __restrict__ src,
                                         const int* __restrict__ ap, int c) {
    int rows[D];
#pragma unroll
    for (int j = 0; j < D; ++j) rows[j] = ap[j];
    half8 raw[D];
#pragma unroll
    for (int j = 0; j < D; ++j) raw[j] = *(const half8*)(src + (size_t)rows[j]*LD + c);
#pragma unroll
    for (int j = 0; j < D; ++j) v = max8(v, raw[j]);
}

template<int LD>
__device__ __forceinline__ void gath_max(half8& v, const f16_t* __restrict__ src,
                                         const int* __restrict__ ap, int s, int c) {
    switch (s) {
        case 1:  gathD_pk<1,LD>(v,src,ap,c);  break;
        case 2:  gathD_pk<2,LD>(v,src,ap,c);  break;
        case 3:  gathD_pk<3,LD>(v,src,ap,c);  break;
        case 4:  gathD_pk<4,LD>(v,src,ap,c);  break;
        case 5:  gathD_pk<5,LD>(v,src,ap,c);  break;
        case 6:  gathD_pk<6,LD>(v,src,ap,c);  break;
        case 7:  gathD_pk<7,LD>(v,src,ap,c);  break;
        case 8:  gathD_pk<8,LD>(v,src,ap,c);  break;
        case 9:  gathD_pk<9,LD>(v,src,ap,c);  break;
        case 10: gathD_pk<10,LD>(v,src,ap,c); break;
        default: break;
    }
}

// ---------------- merged: NBX = sum_neigh xq (BLOB NKB=3)  +  segment scatter ----------------
__global__ __launch_bounds__(256) void nbsum_sc(const f16_t* __restrict__ xq,
                                                f16_t* __restrict__ NBX, Adj adj,
                                                const int* __restrict__ mem,
                                                int* __restrict__ counts,
                                                int* __restrict__ slots) {
    if (blockIdx.x >= 3072) {
        int i = (blockIdx.x - 3072) * 256 + threadIdx.x;   // 65536 exact
        int s = mem[i];
        int p = atomicAdd(&counts[s], 1);
        if (p < 32) slots[s*32 + p] = i;
        return;
    }
    int idx = blockIdx.x * 256 + threadIdx.x;   // 65536*12 exact, dense
    int r = (int)((unsigned)idx / 12u);
    int cc = idx - r * 12;
    int c = cc << 3;
    int s = seg_of(r);
    float v[8];
#pragma unroll
    for (int e = 0; e < 8; ++e) v[e] = 0.f;
    if (s > 0)
        gath_sum<96>(v, xq, adj.p[s-1] + (size_t)(r - c_offs[s]) * s, s, c);
    f16_t o[8];
#pragma unroll
    for (int e = 0; e < 8; ++e) o[e] = (f16_t)v[e];
    *(uint4*)(NBX + (size_t)(r>>4)*1536 + (c>>5)*512 + ((c>>3)&3)*128 + (r&15)*8) = *(uint4*)o;
}

// ---------------- graph pool: max over self+neighbors; packed f16; output rm or blob ----------------
template<bool BLOB>
__global__ __launch_bounds__(256) void pool_k(const f16_t* __restrict__ H,
                                              f16_t* __restrict__ P, Adj adj) {
    int idx = blockIdx.x * 256 + threadIdx.x;   // 65536*32 exact
    int r = idx >> 5;
    int c = (idx & 31) << 3;
    int s = seg_of(r);
    half8 v = *(const half8*)(H + (size_t)r*256 + c);
    if (s > 0)
        gath_max<256>(v, H, adj.p[s-1] + (size_t)(r - c_offs[s]) * s, s, c);
    if (BLOB)
        *(half8*)(P + (size_t)(r>>4)*4096 + (c>>5)*512 + ((c>>3)&3)*128 + (r&15)*8) = v;
    else
        *(half8*)(P + (size_t)r*256 + c) = v;
}

// ---------------- neighbor-sum of pooled features (reads rm, writes BLOB NKB=8) ----------------
__global__ __launch_bounds__(256) void nbsum_k(const f16_t* __restrict__ P,
                                               f16_t* __restrict__ NB, Adj adj) {
    int idx = blockIdx.x * 256 + threadIdx.x;   // 65536*32 exact
    int r = idx >> 5;
    int c = (idx & 31) << 3;
    int s = seg_of(r);
    float v[8];
#pragma unroll
    for (int e = 0; e < 8; ++e) v[e] = 0.f;
    if (s > 0)
        gath_sum<256>(v, P, adj.p[s-1] + (size_t)(r - c_offs[s]) * s, s, c);
    f16_t o[8];
#pragma unroll
    for (int e = 0; e < 8; ++e) o[e] = (f16_t)v[e];
    *(uint4*)(NB + (size_t)(r>>4)*4096 + (c>>5)*512 + ((c>>3)&3)*128 + (r&15)*8) = *(uint4*)o;
}

// ---------------- gc1/gc2 GEMM: direct mixed-A->register, reg-dbuf, no K-loop barriers ----------------
// (256,2): allocator free to hold the dbuf set (R12 lesson). 17.4 KB epilogue.
template<int NKB, int KSPB, int LDA, int NKBA1, int N, bool SEG>
__global__ __launch_bounds__(256, 2)
void gemm_gc(const f16_t* __restrict__ A0, const f16_t* __restrict__ A1,
             const f16_t* __restrict__ Wp,
             const float* __restrict__ bias,
             const float* __restrict__ bng, const float* __restrict__ bnb,
             const float* __restrict__ bnm, const float* __restrict__ bnv,
             f16_t* __restrict__ C)
{
    constexpr int NNT = N / 16;
    constexpr int NYL = N / 128;                   // 2
    __shared__ f16_t eps[64*136];                  // epilogue only (17.4 KB)
    const int t = threadIdx.x, lane = t & 63, w = t >> 6;
    const int wm = w >> 1, wn = w & 1;             // 2M x 2N waves
    const int quad = lane >> 4, l16 = lane & 15;
    const int id = blockIdx.x;                     // 1024 = 8 xcd x 64 xi x NYL y
    const int xcd = id & 7;
    const int j = id >> 3;
    const int xi = xcd * 64 + j / NYL;
    const int y = j % NYL;
    const int r0 = xi * 128, n0 = y * 128;
    const int rt0 = (r0 >> 4) + wm*4;              // blob row-tile base for this wave
    const int nt0 = (n0 >> 4) + wn*4;
    const int seg = SEG ? seg_of(r0) : 0;

    f32x4 acc[4][4];
#pragma unroll
    for (int mi = 0; mi < 4; ++mi)
#pragma unroll
        for (int ni = 0; ni < 4; ++ni) acc[mi][ni] = (f32x4){0.f,0.f,0.f,0.f};

    const f16_t* bpW = Wp + ((size_t)(seg*NNT + nt0) * NKB) * 512 + lane*8;
    const f16_t* apB = A1 + (size_t)rt0 * NKBA1 * 512 + lane*8;
    const f16_t* apR = A0 + (size_t)(r0 + wm*64 + l16) * LDA + quad*8;

    auto loadA = [&](half8& dst, int mi, int kb) {
        if (kb < KSPB)
            dst = *(const half8*)(apR + (size_t)(mi*16) * LDA + kb*32);
        else
            dst = *(const half8*)(apB + ((size_t)mi*NKBA1 + (kb - KSPB))*512);
    };
    auto loadB = [&](half8& dst, int ni, int kb) {
        dst = *(const half8*)(bpW + ((size_t)ni*NKB + kb)*512);
    };

    half8 aA[4], bA[4], aB[4], bB[4];
#pragma unroll
    for (int i = 0; i < 4; ++i) { loadA(aA[i], i, 0); loadB(bA[i], i, 0); }
#pragma unroll
    for (int kb = 0; kb < NKB; kb += 2) {
        if (kb + 1 < NKB) {
#pragma unroll
            for (int i = 0; i < 4; ++i) { loadA(aB[i], i, kb + 1); loadB(bB[i], i, kb + 1); }
        }
#pragma unroll
        for (int mi = 0; mi < 4; ++mi)
#pragma unroll
            for (int ni = 0; ni < 4; ++ni)
                acc[mi][ni] = __builtin_amdgcn_mfma_f32_16x16x32_f16(
                    aA[mi], bA[ni], acc[mi][ni], 0, 0, 0);
        if (kb + 2 < NKB) {
#pragma unroll
            for (int i = 0; i < 4; ++i) { loadA(aA[i], i, kb + 2); loadB(bA[i], i, kb + 2); }
        }
        if (kb + 1 < NKB) {
#pragma unroll
            for (int mi = 0; mi < 4; ++mi)
#pragma unroll
                for (int ni = 0; ni < 4; ++ni)
                    acc[mi][ni] = __builtin_amdgcn_mfma_f32_16x16x32_f16(
                        aB[mi], bB[ni], acc[mi][ni], 0, 0, 0);
        }
    }

    // epilogue: two 64-row strip passes through 17.4 KB LDS, coalesced 16-B stores
#pragma unroll
    for (int sp = 0; sp < 2; ++sp) {
        if (wm == sp) {
#pragma unroll
            for (int ni = 0; ni < 4; ++ni) {
                const int lcol = wn*64 + ni*16 + l16;
                const int col = n0 + lcol;
                const float scale = bng[col] * rsqrtf(bnv[col] + 1e-3f);
                const float shift = bnb[col] - bnm[col] * scale;
                const float bv = bias[(SEG ? seg*N : 0) + col];
#pragma unroll
                for (int mi = 0; mi < 4; ++mi) {
                    const int rowb = mi*16 + quad*4;
#pragma unroll
                    for (int rr = 0; rr < 4; ++rr) {
                        float v = acc[mi][ni][rr] + bv;
                        v = fmaxf(v, 0.f);
                        v = fmaf(v, scale, shift);
                        eps[(rowb + rr)*136 + lcol] = (f16_t)v;
                    }
                }
            }
        }
        __syncthreads();
#pragma unroll
        for (int k2 = 0; k2 < 4; ++k2) {
            int idx = k2*256 + t;                   // 1024 uint4 = 64 rows x 16 chunks
            int row = idx >> 4, ch = idx & 15;
            *(uint4*)(C + (size_t)(r0 + sp*64 + row)*N + n0 + ch*8) =
                *(const uint4*)&eps[row*136 + ch*8];
        }
        __syncthreads();
    }
}

// ---------------- dense GEMM: direct blob->register with REGISTER double-buffer ----------------
__global__ __launch_bounds__(256, 2)
void gemm_dir(const f16_t* __restrict__ A, const f16_t* __restrict__ Wp,
              const float* __restrict__ bias,
              const float* __restrict__ bng, const float* __restrict__ bnb,
              const float* __restrict__ bnm, const float* __restrict__ bnv,
              f16_t* __restrict__ C)
{
    constexpr int NKB = 8, N = 512;
    __shared__ f16_t eps[64*136];                  // epilogue only (17.4 KB)
    const int t = threadIdx.x, lane = t & 63, w = t >> 6;
    const int wm = w >> 1, wn = w & 1;             // 2M x 2N waves
    const int quad = lane >> 4, l16 = lane & 15;
    const int id = blockIdx.x;                     // 2048 = 8 xcd x 64 xi x 4 y
    const int xcd = id & 7;
    const int j = id >> 3;
    const int xi = xcd * 64 + (j >> 2);
    const int y = j & 3;
    const int r0 = xi * 128, n0 = y * 128;
    const int rt0 = (r0 >> 4) + wm*4;
    const int nt0 = (n0 >> 4) + wn*4;

    f32x4 acc[4][4];
#pragma unroll
    for (int mi = 0; mi < 4; ++mi)
#pragma unroll
        for (int ni = 0; ni < 4; ++ni) acc[mi][ni] = (f32x4){0.f,0.f,0.f,0.f};

    const f16_t* ap = A  + (size_t)rt0 * NKB * 512 + lane*8;
    const f16_t* bp = Wp + (size_t)nt0 * NKB * 512 + lane*8;

    half8 aA[4], bA[4], aB[4], bB[4];
#pragma unroll
    for (int i = 0; i < 4; ++i) {
        aA[i] = *(const half8*)(ap + ((size_t)i*NKB + 0)*512);
        bA[i] = *(const half8*)(bp + ((size_t)i*NKB + 0)*512);
    }
#pragma unroll
    for (int kb = 0; kb < NKB; kb += 2) {
        if (kb + 1 < NKB) {
#pragma unroll
            for (int i = 0; i < 4; ++i) {
                aB[i] = *(const half8*)(ap + ((size_t)i*NKB + kb + 1)*512);
                bB[i] = *(const half8*)(bp + ((size_t)i*NKB + kb + 1)*512);
            }
        }
#pragma unroll
        for (int mi = 0; mi < 4; ++mi)
#pragma unroll
            for (int ni = 0; ni < 4; ++ni)
                acc[mi][ni] = __builtin_amdgcn_mfma_f32_16x16x32_f16(
                    aA[mi], bA[ni], acc[mi][ni], 0, 0, 0);
        if (kb + 2 < NKB) {
#pragma unroll
            for (int i = 0; i < 4; ++i) {
                aA[i] = *(const half8*)(ap + ((size_t)i*NKB + kb + 2)*512);
                bA[i] = *(const half8*)(bp + ((size_t)i*NKB + kb + 2)*512);
            }
        }
        if (kb + 1 < NKB) {
#pragma unroll
            for (int mi = 0; mi < 4; ++mi)
#pragma unroll
                for (int ni = 0; ni < 4; ++ni)
                    acc[mi][ni] = __builtin_amdgcn_mfma_f32_16x16x32_f16(
                        aB[mi], bB[ni], acc[mi][ni], 0, 0, 0);
        }
    }

    // epilogue: two 64-row strip passes
#pragma unroll
    for (int sp = 0; sp < 2; ++sp) {
        if (wm == sp) {
#pragma unroll
            for (int ni = 0; ni < 4; ++ni) {
                const int lcol = wn*64 + ni*16 + l16;
                const int col = n0 + lcol;
                const float scale = bng[col] * rsqrtf(bnv[col] + 1e-3f);
                const float shift = bnb[col] - bnm[col] * scale;
                const float bv = bias[col];
#pragma unroll
                for (int mi = 0; mi < 4; ++mi) {
                    const int rowb = mi*16 + quad*4;
#pragma unroll
                    for (int rr = 0; rr < 4; ++rr) {
                        float v = acc[mi][ni][rr] + bv;
                        v = fmaxf(v, 0.f);
                        v = fmaf(v, scale, shift);
                        eps[(rowb + rr)*136 + lcol] = (f16_t)v;
                    }
                }
            }
        }
        __syncthreads();
#pragma unroll
        for (int k2 = 0; k2 < 4; ++k2) {
            int idx = k2*256 + t;                   // 1024 uint4 = 64 rows x 16 chunks
            int row = idx >> 4, ch = idx & 15;
            *(uint4*)(C + (size_t)(r0 + sp*64 + row)*N + n0 + ch*8) =
                *(const uint4*)&eps[row*136 + ch*8];
        }
        __syncthreads();
    }
}

// ---------------- segment sum/max over H3[65536x512] -> fp = tanh([ssum|smax]) ----------------
__global__ __launch_bounds__(256)
void reduce_k(const f16_t* __restrict__ H3, const int* __restrict__ slots,
              float* __restrict__ fp) {
    __shared__ float shs[3][512];
    __shared__ float shm[3][512];
    int s = blockIdx.x;
    int t = threadIdx.x;
    int w = t >> 6, l = t & 63;
    int c = l * 8;
    const int* sl = slots + s*32 + w*8;
    float sm[8], mx[8];
#pragma unroll
    for (int e = 0; e < 8; ++e) { sm[e] = 0.f; mx[e] = -INFINITY; }
#pragma unroll
    for (int i = 0; i < 8; ++i) {
        int a = sl[i];
        uint4 raw = *(const uint4*)(H3 + (size_t)a*512 + c);
        const f16_t* u = (const f16_t*)&raw;
#pragma unroll
        for (int e = 0; e < 8; ++e) {
            float f = (float)u[e];
            sm[e] += f;
            mx[e] = fmaxf(mx[e], f);
        }
    }
    if (w) {
        *(float4*)&shs[w-1][c]   = *(float4*)&sm[0];
        *(float4*)&shs[w-1][c+4] = *(float4*)&sm[4];
        *(float4*)&shm[w-1][c]   = *(float4*)&mx[0];
        *(float4*)&shm[w-1][c+4] = *(float4*)&mx[4];
    }
    __syncthreads();
    if (w == 0) {
#pragma unroll
        for (int j = 0; j < 3; ++j)
#pragma unroll
            for (int e = 0; e < 8; ++e) {
                sm[e] += shs[j][c+e];
                mx[e] = fmaxf(mx[e], shm[j][c+e]);
            }
        float o1[8], o2[8];
#pragma unroll
        for (int e = 0; e < 8; ++e) {
            o1[e] = tanhf(sm[e]); o2[e] = tanhf(mx[e]);
        }
        float* fr = fp + (size_t)s*1024;
        *(float4*)(fr + c)       = *(float4*)&o1[0];
        *(float4*)(fr + c + 4)   = *(float4*)&o1[4];
        *(float4*)(fr + 512 + c)     = *(float4*)&o2[0];
        *(float4*)(fr + 512 + c + 4) = *(float4*)&o2[4];
    }
}

// ---------------- readout GEMM: logits = fp @ out_w + out_b; probs = pair-softmax ----------------
__global__ __launch_bounds__(64)
void final_mfma(const float* __restrict__ fp, const f16_t* __restrict__ Wop,
                const float* __restrict__ out_b,
                float* __restrict__ probs, float* __restrict__ logits) {
    const int t = threadIdx.x;
    const int lane = t & 63;
    const int quad = lane >> 4, l16 = lane & 15;
    const int r0 = blockIdx.x * 16;

    f32x4 acc[2];
#pragma unroll
    for (int ni = 0; ni < 2; ++ni) acc[ni] = (f32x4){0.f,0.f,0.f,0.f};

    const size_t rowoff = (size_t)(r0 + l16) * 1024 + quad*8;
    size_t boff[2];
#pragma unroll
    for (int ni = 0; ni < 2; ++ni)
        boff[ni] = (size_t)ni * 32 * 512 + lane*8;

    auto loadA = [&](half8& a, int kb) {
        const float* src = fp + rowoff + kb*32;
        float4 u0 = *(const float4*)(src);
        float4 u1 = *(const float4*)(src + 4);
        half8 h;
        h[0] = (f16_t)u0.x; h[1] = (f16_t)u0.y; h[2] = (f16_t)u0.z; h[3] = (f16_t)u0.w;
        h[4] = (f16_t)u1.x; h[5] = (f16_t)u1.y; h[6] = (f16_t)u1.z; h[7] = (f16_t)u1.w;
        a = h;
    };
    auto loadB = [&](half8* b, int kb) {
#pragma unroll
        for (int ni = 0; ni < 2; ++ni) b[ni] = *(const half8*)(Wop + boff[ni] + (size_t)kb*512);
    };
    auto domfma = [&](half8& a, half8* b) {
#pragma unroll
        for (int ni = 0; ni < 2; ++ni)
            acc[ni] = __builtin_amdgcn_mfma_f32_16x16x32_f16(a, b[ni], acc[ni], 0, 0, 0);
    };

    half8 a0, b0[2], a1, b1[2];
    loadA(a0, 0); loadB(b0, 0);
#pragma unroll
    for (int kb = 0; kb < 32; kb += 2) {
        loadA(a1, kb + 1); loadB(b1, kb + 1);
        domfma(a0, b0);
        if (kb + 2 < 32) { loadA(a0, kb + 2); loadB(b0, kb + 2); }
        domfma(a1, b1);
    }

#pragma unroll
    for (int ni = 0; ni < 2; ++ni) {
        const int c = ni*16 + l16;
        const bool ok = (c < 24);
        const float bv = ok ? out_b[c] : 0.f;
#pragma unroll
        for (int r = 0; r < 4; ++r) {
            float lg = acc[ni][r] + bv;
            float lp = __shfl_xor(lg, 1);
            float m = fmaxf(lg, lp);
            float e  = expf(lg - m);
            float ep = expf(lp - m);
            float pr = e / (e + ep);
            if (ok) {
                int row = r0 + quad*4 + r;
                logits[(size_t)row*24 + c] = lg;
                probs[(size_t)row*24 + c]  = pr;
            }
        }
    }
}

extern "C" void kernel_launch(void* const* d_in, const int* in_sizes, int n_in,
                              void* d_out, int out_size, void* d_ws, size_t ws_size,
                              hipStream_t stream) {
    const float* atom       = (const float*)d_in[0];
    const int*   membership = (const int*)  d_in[2];
    Adj adj;
    for (int d = 0; d < 10; ++d) adj.p[d] = (const int*)d_in[4+d];
    const float* gc1_w0     = (const float*)d_in[14];
    const float* gc1_wself  = (const float*)d_in[15];
    const float* gc1_wneigh = (const float*)d_in[16];
    const float* gc1_b      = (const float*)d_in[17];
    const float* gc2_w0     = (const float*)d_in[18];
    const float* gc2_wself  = (const float*)d_in[19];
    const float* gc2_wneigh = (const float*)d_in[20];
    const float* gc2_b      = (const float*)d_in[21];
    const float* bn1g = (const float*)d_in[22]; const float* bn1b = (const float*)d_in[23];
    const float* bn1m = (const float*)d_in[24]; const float* bn1v = (const float*)d_in[25];
    const float* bn2g = (const float*)d_in[26]; const float* bn2b = (const float*)d_in[27];
    const float* bn2m = (const float*)d_in[28]; const float* bn2v = (const float*)d_in[29];
    const float* bn3g = (const float*)d_in[30]; const float* bn3b = (const float*)d_in[31];
    const float* bn3m = (const float*)d_in[32]; const float* bn3v = (const float*)d_in[33];
    const float* dense_w = (const float*)d_in[34];
    const float* dense_b = (const float*)d_in[35];
    const float* out_w   = (const float*)d_in[36];
    const float* out_b   = (const float*)d_in[37];

    // workspace (f16 units), single copies:
    f16_t* wsb = (f16_t*)d_ws;
    f16_t* xq    = wsb;                        //  6,291,456
    f16_t* NBX   = wsb + 6291456;              //  6,291,456 (blob NKB=3)
    f16_t* H1b   = wsb + 12582912;             // 16,777,216  (also H2; H3 starts here)
    f16_t* P1rm  = wsb + 29360128;             // 16,777,216
    f16_t* NB2b  = wsb + 46137344;             // 16,777,216 (blob NKB=8; later P2_bl)
    f16_t* H2b   = H1b;
    f16_t* P2bl  = NB2b;
    f16_t* H3b   = H1b;                        // 33,554,432 spans H1+P1rm
    f16_t* W1p   = wsb + 62914560;             //    540,672
    f16_t* W2p   = wsb + 63455232;             //  1,441,792
    f16_t* Wdp   = wsb + 64897024;             //    131,072
    f16_t* Wop   = wsb + 65028096;             //     32,768
    int*  counts = (int*)(wsb + 65060864);     // 2048 ints
    int*  slots  = counts + 2048;              // 65536 ints

    float* outp   = (float*)d_out;
    float* probs  = outp;            // 2048*24
    float* logits = outp + 49152;    // 2048*24
    float* fp     = outp + 98304;    // 2048*1024

    pack_cvt<<<11456, 256, 0, stream>>>(gc1_w0, gc1_wself, gc1_wneigh,
                                        gc2_w0, gc2_wself, gc2_wneigh,
                                        dense_w, out_w,
                                        W1p, W2p, Wdp, Wop, counts,
                                        atom, xq);

    // gc1: A0 = xq row-major (kb<3), A1 = NBX blob; direct, 1024 blocks
    nbsum_sc<<<3328, 256, 0, stream>>>(xq, NBX, adj, membership, counts, slots);
    gemm_gc<6,3,96,3,256,true><<<1024, 256, 0, stream>>>(
        xq, NBX, W1p, gc1_b, bn1g, bn1b, bn1m, bn1v, H1b);
    pool_k<false><<<(NATOMS*32)/256, 256, 0, stream>>>(H1b, P1rm, adj);

    // gc2: A0 = P1rm row-major (kb<8), A1 = NB2 blob; direct, 1024 blocks
    nbsum_k<<<(NATOMS*32)/256, 256, 0, stream>>>(P1rm, NB2b, adj);
    gemm_gc<16,8,256,8,256,true><<<1024, 256, 0, stream>>>(
        P1rm, NB2b, W2p, gc2_b, bn2g, bn2b, bn2m, bn2v, H2b);
    pool_k<true><<<(NATOMS*32)/256, 256, 0, stream>>>(H2b, P2bl, adj);

    // dense: direct blob->reg GEMM, reg-dbuf prefetch, XCD-grouped; 2048 x 256
    gemm_dir<<<2048, 256, 0, stream>>>(
        P2bl, Wdp, dense_b, bn3g, bn3b, bn3m, bn3v, H3b);

    // segment reduce + tanh -> fp (fp32, in d_out); 4 waves/segment
    reduce_k<<<2048, 256, 0, stream>>>(H3b, slots, fp);

    // readout
    final_mfma<<<128, 64, 0, stream>>>(fp, Wop, out_b, probs, logits);
}

// Round 14
// 336.398 us; speedup vs baseline: 1.0535x; 1.0535x over previous
//
#include <hip/hip_runtime.h>
#include <hip/hip_fp16.h>
#include <math.h>

#define NATOMS 65536

typedef _Float16 f16_t;
typedef __attribute__((ext_vector_type(8))) _Float16 half8;
typedef __attribute__((ext_vector_type(4))) float f32x4;

__constant__ int c_offs[12] = {0,1536,9728,26112,50688,62976,64000,64512,65024,65280,65408,65536};

struct Adj { const int* p[10]; };

__device__ __forceinline__ int seg_of(int row) {
    int s = 0;
#pragma unroll
    for (int i = 1; i <= 10; ++i) s += (row >= c_offs[i]) ? 1 : 0;
    return s;
}

// packed f16 max (exact)
__device__ __forceinline__ half8 max8(half8 a, half8 b) {
    half8 r;
#pragma unroll
    for (int e = 0; e < 8; ++e) r[e] = (a[e] >= b[e]) ? a[e] : b[e];
    return r;
}

// Blob layout (MFMA A-fragment order), NKB = cols/32:
//   addr(r,k) = ((r>>4)*NKB + (k>>5))*512 + ((k>>3)&3)*128 + (r&15)*8 + (k&7)
// Key identity: chunk*512 + lane*8 IS the per-lane MFMA fragment -> blob tensors
// load global->VGPR directly. Row-major fragment: rm[(row16+l16)*LD + kb*32+quad*8].
// All segment boundaries are multiples of 128 -> 128-row tiles are seg-uniform.
// R12/R13 lessons: VGPR > occupancy for the direct GEMMs. (256,4) -> VGPR 64,
// and even (256,2)+2-strip epilogue -> VGPR 76; both re-serialize the reg-dbuf.
// This file is the R10 best-known config: 34.8 KB single-pass epilogue, (256,2).

// ---------------- merged: weight packing (+ counts zeroing) + cvt_pad ----------------
__global__ void pack_cvt(const float* __restrict__ g1w0, const float* __restrict__ g1ws,
                         const float* __restrict__ g1wn,
                         const float* __restrict__ g2w0, const float* __restrict__ g2ws,
                         const float* __restrict__ g2wn,
                         const float* __restrict__ dw, const float* __restrict__ ow,
                         f16_t* __restrict__ W1p, f16_t* __restrict__ W2p,
                         f16_t* __restrict__ Wdp, f16_t* __restrict__ Wop,
                         int* __restrict__ counts,
                         const float* __restrict__ xf, f16_t* __restrict__ xq) {
    if (blockIdx.x >= 8384) {
        int idx = (blockIdx.x - 8384) * 256 + threadIdx.x;   // 65536*12 exact
        int r = idx / 12;
        int cc = idx - r * 12;
        int c = cc << 3;
        f16_t o[8];
#pragma unroll
        for (int e = 0; e < 8; ++e)
            o[e] = (c + e < 75) ? (f16_t)xf[(size_t)r*75 + c + e] : (f16_t)0.f;
        *(uint4*)(xq + (size_t)r*96 + c) = *(uint4*)o;
        return;
    }
    int idx = blockIdx.x * 256 + threadIdx.x;   // 8384*256 = 2146304 exact
    if (idx < 2048) counts[idx] = 0;
    if (idx < 540672) {
        int j = idx & 7, lane = (idx >> 3) & 63;
        int kb = (idx >> 9) % 6;
        int rest = idx / (512 * 6);
        int ni = rest & 15, s = rest >> 4;
        int k = kb * 32 + (lane >> 4) * 8 + j;
        int n = ni * 16 + (lane & 15);
        float v = 0.f;
        if (k < 75) v = (s == 0) ? g1w0[k*256 + n] : g1ws[((s-1)*75 + k)*256 + n];
        else if (k >= 96 && k < 171 && s > 0) v = g1wn[((s-1)*75 + (k-96))*256 + n];
        W1p[idx] = (f16_t)v;
    } else if (idx < 1982464) {
        int i2 = idx - 540672;
        int j = i2 & 7, lane = (i2 >> 3) & 63;
        int kb = (i2 >> 9) & 15;
        int rest = i2 >> 13;
        int ni = rest & 15, s = rest >> 4;
        int k = kb * 32 + (lane >> 4) * 8 + j;
        int n = ni * 16 + (lane & 15);
        float v = 0.f;
        if (k < 256) v = (s == 0) ? g2w0[k*256 + n] : g2ws[((s-1)*256 + k)*256 + n];
        else if (s > 0) v = g2wn[((s-1)*256 + (k-256))*256 + n];
        W2p[i2] = (f16_t)v;
    } else if (idx < 2113536) {
        int i2 = idx - 1982464;
        int j = i2 & 7, lane = (i2 >> 3) & 63;
        int kb = (i2 >> 9) & 7;
        int ni = (i2 >> 12) & 31;
        int k = kb * 32 + (lane >> 4) * 8 + j;
        int n = ni * 16 + (lane & 15);
        Wdp[i2] = (f16_t)dw[(size_t)k*512 + n];
    } else {
        int i2 = idx - 2113536;
        int j = i2 & 7, lane = (i2 >> 3) & 63;
        int kb = (i2 >> 9) & 31;
        int ni = i2 >> 14;
        int k = kb * 32 + (lane >> 4) * 8 + j;
        int n = ni * 16 + (lane & 15);
        Wop[i2] = (n < 24) ? (f16_t)ow[k*24 + n] : (f16_t)0.f;
    }
}

// ---------------- compile-time-degree gather helpers (row-major sources) ----------------
template<int D, int LD>
__device__ __forceinline__ void gathD(float* v, const f16_t* __restrict__ src,
                                      const int* __restrict__ ap, int c) {
    int rows[D];
#pragma unroll
    for (int j = 0; j < D; ++j) rows[j] = ap[j];
    uint4 raw[D];
#pragma unroll
    for (int j = 0; j < D; ++j) raw[j] = *(const uint4*)(src + (size_t)rows[j]*LD + c);
#pragma unroll
    for (int j = 0; j < D; ++j) {
        const f16_t* u = (const f16_t*)&raw[j];
#pragma unroll
        for (int e = 0; e < 8; ++e) v[e] += (float)u[e];
    }
}

template<int LD>
__device__ __forceinline__ void gath_sum(float* v, const f16_t* __restrict__ src,
                                         const int* __restrict__ ap, int s, int c) {
    switch (s) {
        case 1:  gathD<1,LD>(v,src,ap,c);  break;
        case 2:  gathD<2,LD>(v,src,ap,c);  break;
        case 3:  gathD<3,LD>(v,src,ap,c);  break;
        case 4:  gathD<4,LD>(v,src,ap,c);  break;
        case 5:  gathD<5,LD>(v,src,ap,c);  break;
        case 6:  gathD<6,LD>(v,src,ap,c);  break;
        case 7:  gathD<7,LD>(v,src,ap,c);  break;
        case 8:  gathD<8,LD>(v,src,ap,c);  break;
        case 9:  gathD<9,LD>(v,src,ap,c);  break;
        case 10: gathD<10,LD>(v,src,ap,c); break;
        default: break;
    }
}

template<int D, int LD>
__device__ __forceinline__ void gathD_pk(half8& v, const f16_t* __restrict__ src,
                                         const int* __restrict__ ap, int c) {
    int rows[D];
#pragma unroll
    for (int j = 0; j < D; ++j) rows[j] = ap[j];
    half8 raw[D];
#pragma unroll
    for (int j = 0; j < D; ++j) raw[j] = *(const half8*)(src + (size_t)rows[j]*LD + c);
#pragma unroll
    for (int j = 0; j < D; ++j) v = max8(v, raw[j]);
}

template<int LD>
__device__ __forceinline__ void gath_max(half8& v, const f16_t* __restrict__ src,
                                         const int* __restrict__ ap, int s, int c) {
    switch (s) {
        case 1:  gathD_pk<1,LD>(v,src,ap,c);  break;
        case 2:  gathD_pk<2,LD>(v,src,ap,c);  break;
        case 3:  gathD_pk<3,LD>(v,src,ap,c);  break;
        case 4:  gathD_pk<4,LD>(v,src,ap,c);  break;
        case 5:  gathD_pk<5,LD>(v,src,ap,c);  break;
        case 6:  gathD_pk<6,LD>(v,src,ap,c);  break;
        case 7:  gathD_pk<7,LD>(v,src,ap,c);  break;
        case 8:  gathD_pk<8,LD>(v,src,ap,c);  break;
        case 9:  gathD_pk<9,LD>(v,src,ap,c);  break;
        case 10: gathD_pk<10,LD>(v,src,ap,c); break;
        default: break;
    }
}

// ---------------- merged: NBX = sum_neigh xq (BLOB NKB=3)  +  segment scatter ----------------
__global__ __launch_bounds__(256) void nbsum_sc(const f16_t* __restrict__ xq,
                                                f16_t* __restrict__ NBX, Adj adj,
                                                const int* __restrict__ mem,
                                                int* __restrict__ counts,
                                                int* __restrict__ slots) {
    if (blockIdx.x >= 3072) {
        int i = (blockIdx.x - 3072) * 256 + threadIdx.x;   // 65536 exact
        int s = mem[i];
        int p = atomicAdd(&counts[s], 1);
        if (p < 32) slots[s*32 + p] = i;
        return;
    }
    int idx = blockIdx.x * 256 + threadIdx.x;   // 65536*12 exact, dense
    int r = (int)((unsigned)idx / 12u);
    int cc = idx - r * 12;
    int c = cc << 3;
    int s = seg_of(r);
    float v[8];
#pragma unroll
    for (int e = 0; e < 8; ++e) v[e] = 0.f;
    if (s > 0)
        gath_sum<96>(v, xq, adj.p[s-1] + (size_t)(r - c_offs[s]) * s, s, c);
    f16_t o[8];
#pragma unroll
    for (int e = 0; e < 8; ++e) o[e] = (f16_t)v[e];
    *(uint4*)(NBX + (size_t)(r>>4)*1536 + (c>>5)*512 + ((c>>3)&3)*128 + (r&15)*8) = *(uint4*)o;
}

// ---------------- graph pool: max over self+neighbors; packed f16; output rm or blob ----------------
template<bool BLOB>
__global__ __launch_bounds__(256) void pool_k(const f16_t* __restrict__ H,
                                              f16_t* __restrict__ P, Adj adj) {
    int idx = blockIdx.x * 256 + threadIdx.x;   // 65536*32 exact
    int r = idx >> 5;
    int c = (idx & 31) << 3;
    int s = seg_of(r);
    half8 v = *(const half8*)(H + (size_t)r*256 + c);
    if (s > 0)
        gath_max<256>(v, H, adj.p[s-1] + (size_t)(r - c_offs[s]) * s, s, c);
    if (BLOB)
        *(half8*)(P + (size_t)(r>>4)*4096 + (c>>5)*512 + ((c>>3)&3)*128 + (r&15)*8) = v;
    else
        *(half8*)(P + (size_t)r*256 + c) = v;
}

// ---------------- neighbor-sum of pooled features (reads rm, writes BLOB NKB=8) ----------------
__global__ __launch_bounds__(256) void nbsum_k(const f16_t* __restrict__ P,
                                               f16_t* __restrict__ NB, Adj adj) {
    int idx = blockIdx.x * 256 + threadIdx.x;   // 65536*32 exact
    int r = idx >> 5;
    int c = (idx & 31) << 3;
    int s = seg_of(r);
    float v[8];
#pragma unroll
    for (int e = 0; e < 8; ++e) v[e] = 0.f;
    if (s > 0)
        gath_sum<256>(v, P, adj.p[s-1] + (size_t)(r - c_offs[s]) * s, s, c);
    f16_t o[8];
#pragma unroll
    for (int e = 0; e < 8; ++e) o[e] = (f16_t)v[e];
    *(uint4*)(NB + (size_t)(r>>4)*4096 + (c>>5)*512 + ((c>>3)&3)*128 + (r&15)*8) = *(uint4*)o;
}

// ---------------- gc1/gc2 GEMM: direct mixed-A->register, reg-dbuf, no K-loop barriers ----------------
template<int NKB, int KSPB, int LDA, int NKBA1, int N, bool SEG>
__global__ __launch_bounds__(256, 2)
void gemm_gc(const f16_t* __restrict__ A0, const f16_t* __restrict__ A1,
             const f16_t* __restrict__ Wp,
             const float* __restrict__ bias,
             const float* __restrict__ bng, const float* __restrict__ bnb,
             const float* __restrict__ bnm, const float* __restrict__ bnv,
             f16_t* __restrict__ C)
{
    constexpr int NNT = N / 16;
    constexpr int NYL = N / 128;                   // 2
    __shared__ f16_t eps[128*136];                 // epilogue only (34.8 KB)
    const int t = threadIdx.x, lane = t & 63, w = t >> 6;
    const int wm = w >> 1, wn = w & 1;             // 2M x 2N waves
    const int quad = lane >> 4, l16 = lane & 15;
    const int id = blockIdx.x;                     // 1024 = 8 xcd x 64 xi x NYL y
    const int xcd = id & 7;
    const int j = id >> 3;
    const int xi = xcd * 64 + j / NYL;
    const int y = j % NYL;
    const int r0 = xi * 128, n0 = y * 128;
    const int rt0 = (r0 >> 4) + wm*4;              // blob row-tile base for this wave
    const int nt0 = (n0 >> 4) + wn*4;
    const int seg = SEG ? seg_of(r0) : 0;

    f32x4 acc[4][4];
#pragma unroll
    for (int mi = 0; mi < 4; ++mi)
#pragma unroll
        for (int ni = 0; ni < 4; ++ni) acc[mi][ni] = (f32x4){0.f,0.f,0.f,0.f};

    const f16_t* bpW = Wp + ((size_t)(seg*NNT + nt0) * NKB) * 512 + lane*8;
    const f16_t* apB = A1 + (size_t)rt0 * NKBA1 * 512 + lane*8;
    const f16_t* apR = A0 + (size_t)(r0 + wm*64 + l16) * LDA + quad*8;

    auto loadA = [&](half8& dst, int mi, int kb) {
        if (kb < KSPB)
            dst = *(const half8*)(apR + (size_t)(mi*16) * LDA + kb*32);
        else
            dst = *(const half8*)(apB + ((size_t)mi*NKBA1 + (kb - KSPB))*512);
    };
    auto loadB = [&](half8& dst, int ni, int kb) {
        dst = *(const half8*)(bpW + ((size_t)ni*NKB + kb)*512);
    };

    half8 aA[4], bA[4], aB[4], bB[4];
#pragma unroll
    for (int i = 0; i < 4; ++i) { loadA(aA[i], i, 0); loadB(bA[i], i, 0); }
#pragma unroll
    for (int kb = 0; kb < NKB; kb += 2) {
        if (kb + 1 < NKB) {
#pragma unroll
            for (int i = 0; i < 4; ++i) { loadA(aB[i], i, kb + 1); loadB(bB[i], i, kb + 1); }
        }
#pragma unroll
        for (int mi = 0; mi < 4; ++mi)
#pragma unroll
            for (int ni = 0; ni < 4; ++ni)
                acc[mi][ni] = __builtin_amdgcn_mfma_f32_16x16x32_f16(
                    aA[mi], bA[ni], acc[mi][ni], 0, 0, 0);
        if (kb + 2 < NKB) {
#pragma unroll
            for (int i = 0; i < 4; ++i) { loadA(aA[i], i, kb + 2); loadB(bA[i], i, kb + 2); }
        }
        if (kb + 1 < NKB) {
#pragma unroll
            for (int mi = 0; mi < 4; ++mi)
#pragma unroll
                for (int ni = 0; ni < 4; ++ni)
                    acc[mi][ni] = __builtin_amdgcn_mfma_f32_16x16x32_f16(
                        aB[mi], bB[ni], acc[mi][ni], 0, 0, 0);
        }
    }

    // epilogue: 4 waves write disjoint quadrants, one sync, coalesced stores
#pragma unroll
    for (int ni = 0; ni < 4; ++ni) {
        const int lcol = wn*64 + ni*16 + l16;
        const int col = n0 + lcol;
        const float scale = bng[col] * rsqrtf(bnv[col] + 1e-3f);
        const float shift = bnb[col] - bnm[col] * scale;
        const float bv = bias[(SEG ? seg*N : 0) + col];
#pragma unroll
        for (int mi = 0; mi < 4; ++mi) {
            const int rowb = wm*64 + mi*16 + quad*4;
#pragma unroll
            for (int rr = 0; rr < 4; ++rr) {
                float v = acc[mi][ni][rr] + bv;
                v = fmaxf(v, 0.f);
                v = fmaf(v, scale, shift);
                eps[(rowb + rr)*136 + lcol] = (f16_t)v;
            }
        }
    }
    __syncthreads();
#pragma unroll
    for (int k2 = 0; k2 < 8; ++k2) {
        int idx = k2*256 + t;                       // 2048 uint4 = 128 rows x 16 chunks
        int row = idx >> 4, ch = idx & 15;
        *(uint4*)(C + (size_t)(r0 + row)*N + n0 + ch*8) =
            *(const uint4*)&eps[row*136 + ch*8];
    }
}

// ---------------- dense GEMM: direct blob->register with REGISTER double-buffer ----------------
__global__ __launch_bounds__(256, 2)
void gemm_dir(const f16_t* __restrict__ A, const f16_t* __restrict__ Wp,
              const float* __restrict__ bias,
              const float* __restrict__ bng, const float* __restrict__ bnb,
              const float* __restrict__ bnm, const float* __restrict__ bnv,
              f16_t* __restrict__ C)
{
    constexpr int NKB = 8, N = 512;
    __shared__ f16_t eps[128*136];                 // epilogue only (34.8 KB)
    const int t = threadIdx.x, lane = t & 63, w = t >> 6;
    const int wm = w >> 1, wn = w & 1;             // 2M x 2N waves
    const int quad = lane >> 4, l16 = lane & 15;
    const int id = blockIdx.x;                     // 2048 = 8 xcd x 64 xi x 4 y
    const int xcd = id & 7;
    const int j = id >> 3;
    const int xi = xcd * 64 + (j >> 2);
    const int y = j & 3;
    const int r0 = xi * 128, n0 = y * 128;
    const int rt0 = (r0 >> 4) + wm*4;
    const int nt0 = (n0 >> 4) + wn*4;

    f32x4 acc[4][4];
#pragma unroll
    for (int mi = 0; mi < 4; ++mi)
#pragma unroll
        for (int ni = 0; ni < 4; ++ni) acc[mi][ni] = (f32x4){0.f,0.f,0.f,0.f};

    const f16_t* ap = A  + (size_t)rt0 * NKB * 512 + lane*8;
    const f16_t* bp = Wp + (size_t)nt0 * NKB * 512 + lane*8;

    half8 aA[4], bA[4], aB[4], bB[4];
#pragma unroll
    for (int i = 0; i < 4; ++i) {
        aA[i] = *(const half8*)(ap + ((size_t)i*NKB + 0)*512);
        bA[i] = *(const half8*)(bp + ((size_t)i*NKB + 0)*512);
    }
#pragma unroll
    for (int kb = 0; kb < NKB; kb += 2) {
        if (kb + 1 < NKB) {
#pragma unroll
            for (int i = 0; i < 4; ++i) {
                aB[i] = *(const half8*)(ap + ((size_t)i*NKB + kb + 1)*512);
                bB[i] = *(const half8*)(bp + ((size_t)i*NKB + kb + 1)*512);
            }
        }
#pragma unroll
        for (int mi = 0; mi < 4; ++mi)
#pragma unroll
            for (int ni = 0; ni < 4; ++ni)
                acc[mi][ni] = __builtin_amdgcn_mfma_f32_16x16x32_f16(
                    aA[mi], bA[ni], acc[mi][ni], 0, 0, 0);
        if (kb + 2 < NKB) {
#pragma unroll
            for (int i = 0; i < 4; ++i) {
                aA[i] = *(const half8*)(ap + ((size_t)i*NKB + kb + 2)*512);
                bA[i] = *(const half8*)(bp + ((size_t)i*NKB + kb + 2)*512);
            }
        }
        if (kb + 1 < NKB) {
#pragma unroll
            for (int mi = 0; mi < 4; ++mi)
#pragma unroll
                for (int ni = 0; ni < 4; ++ni)
                    acc[mi][ni] = __builtin_amdgcn_mfma_f32_16x16x32_f16(
                        aB[mi], bB[ni], acc[mi][ni], 0, 0, 0);
        }
    }

    // epilogue: all 4 waves write disjoint quadrants, one sync, coalesced stores
#pragma unroll
    for (int ni = 0; ni < 4; ++ni) {
        const int lcol = wn*64 + ni*16 + l16;
        const int col = n0 + lcol;
        const float scale = bng[col] * rsqrtf(bnv[col] + 1e-3f);
        const float shift = bnb[col] - bnm[col] * scale;
        const float bv = bias[col];
#pragma unroll
        for (int mi = 0; mi < 4; ++mi) {
            const int rowb = wm*64 + mi*16 + quad*4;
#pragma unroll
            for (int rr = 0; rr < 4; ++rr) {
                float v = acc[mi][ni][rr] + bv;
                v = fmaxf(v, 0.f);
                v = fmaf(v, scale, shift);
                eps[(rowb + rr)*136 + lcol] = (f16_t)v;
            }
        }
    }
    __syncthreads();
#pragma unroll
    for (int k2 = 0; k2 < 8; ++k2) {
        int idx = k2*256 + t;                       // 2048 uint4 = 128 rows x 16 chunks
        int row = idx >> 4, ch = idx & 15;
        *(uint4*)(C + (size_t)(r0 + row)*N + n0 + ch*8) =
            *(const uint4*)&eps[row*136 + ch*8];
    }
}

// ---------------- segment sum/max over H3[65536x512] -> fp = tanh([ssum|smax]) ----------------
__global__ __launch_bounds__(256)
void reduce_k(const f16_t* __restrict__ H3, const int* __restrict__ slots,
              float* __restrict__ fp) {
    __shared__ float shs[3][512];
    __shared__ float shm[3][512];
    int s = blockIdx.x;
    int t = threadIdx.x;
    int w = t >> 6, l = t & 63;
    int c = l * 8;
    const int* sl = slots + s*32 + w*8;
    float sm[8], mx[8];
#pragma unroll
    for (int e = 0; e < 8; ++e) { sm[e] = 0.f; mx[e] = -INFINITY; }
#pragma unroll
    for (int i = 0; i < 8; ++i) {
        int a = sl[i];
        uint4 raw = *(const uint4*)(H3 + (size_t)a*512 + c);
        const f16_t* u = (const f16_t*)&raw;
#pragma unroll
        for (int e = 0; e < 8; ++e) {
            float f = (float)u[e];
            sm[e] += f;
            mx[e] = fmaxf(mx[e], f);
        }
    }
    if (w) {
        *(float4*)&shs[w-1][c]   = *(float4*)&sm[0];
        *(float4*)&shs[w-1][c+4] = *(float4*)&sm[4];
        *(float4*)&shm[w-1][c]   = *(float4*)&mx[0];
        *(float4*)&shm[w-1][c+4] = *(float4*)&mx[4];
    }
    __syncthreads();
    if (w == 0) {
#pragma unroll
        for (int j = 0; j < 3; ++j)
#pragma unroll
            for (int e = 0; e < 8; ++e) {
                sm[e] += shs[j][c+e];
                mx[e] = fmaxf(mx[e], shm[j][c+e]);
            }
        float o1[8], o2[8];
#pragma unroll
        for (int e = 0; e < 8; ++e) {
            o1[e] = tanhf(sm[e]); o2[e] = tanhf(mx[e]);
        }
        float* fr = fp + (size_t)s*1024;
        *(float4*)(fr + c)       = *(float4*)&o1[0];
        *(float4*)(fr + c + 4)   = *(float4*)&o1[4];
        *(float4*)(fr + 512 + c)     = *(float4*)&o2[0];
        *(float4*)(fr + 512 + c + 4) = *(float4*)&o2[4];
    }
}

// ---------------- readout GEMM: logits = fp @ out_w + out_b; probs = pair-softmax ----------------
__global__ __launch_bounds__(64)
void final_mfma(const float* __restrict__ fp, const f16_t* __restrict__ Wop,
                const float* __restrict__ out_b,
                float* __restrict__ probs, float* __restrict__ logits) {
    const int t = threadIdx.x;
    const int lane = t & 63;
    const int quad = lane >> 4, l16 = lane & 15;
    const int r0 = blockIdx.x * 16;

    f32x4 acc[2];
#pragma unroll
    for (int ni = 0; ni < 2; ++ni) acc[ni] = (f32x4){0.f,0.f,0.f,0.f};

    const size_t rowoff = (size_t)(r0 + l16) * 1024 + quad*8;
    size_t boff[2];
#pragma unroll
    for (int ni = 0; ni < 2; ++ni)
        boff[ni] = (size_t)ni * 32 * 512 + lane*8;

    auto loadA = [&](half8& a, int kb) {
        const float* src = fp + rowoff + kb*32;
        float4 u0 = *(const float4*)(src);
        float4 u1 = *(const float4*)(src + 4);
        half8 h;
        h[0] = (f16_t)u0.x; h[1] = (f16_t)u0.y; h[2] = (f16_t)u0.z; h[3] = (f16_t)u0.w;
        h[4] = (f16_t)u1.x; h[5] = (f16_t)u1.y; h[6] = (f16_t)u1.z; h[7] = (f16_t)u1.w;
        a = h;
    };
    auto loadB = [&](half8* b, int kb) {
#pragma unroll
        for (int ni = 0; ni < 2; ++ni) b[ni] = *(const half8*)(Wop + boff[ni] + (size_t)kb*512);
    };
    auto domfma = [&](half8& a, half8* b) {
#pragma unroll
        for (int ni = 0; ni < 2; ++ni)
            acc[ni] = __builtin_amdgcn_mfma_f32_16x16x32_f16(a, b[ni], acc[ni], 0, 0, 0);
    };

    half8 a0, b0[2], a1, b1[2];
    loadA(a0, 0); loadB(b0, 0);
#pragma unroll
    for (int kb = 0; kb < 32; kb += 2) {
        loadA(a1, kb + 1); loadB(b1, kb + 1);
        domfma(a0, b0);
        if (kb + 2 < 32) { loadA(a0, kb + 2); loadB(b0, kb + 2); }
        domfma(a1, b1);
    }

#pragma unroll
    for (int ni = 0; ni < 2; ++ni) {
        const int c = ni*16 + l16;
        const bool ok = (c < 24);
        const float bv = ok ? out_b[c] : 0.f;
#pragma unroll
        for (int r = 0; r < 4; ++r) {
            float lg = acc[ni][r] + bv;
            float lp = __shfl_xor(lg, 1);
            float m = fmaxf(lg, lp);
            float e  = expf(lg - m);
            float ep = expf(lp - m);
            float pr = e / (e + ep);
            if (ok) {
                int row = r0 + quad*4 + r;
                logits[(size_t)row*24 + c] = lg;
                probs[(size_t)row*24 + c]  = pr;
            }
        }
    }
}

extern "C" void kernel_launch(void* const* d_in, const int* in_sizes, int n_in,
                              void* d_out, int out_size, void* d_ws, size_t ws_size,
                              hipStream_t stream) {
    const float* atom       = (const float*)d_in[0];
    const int*   membership = (const int*)  d_in[2];
    Adj adj;
    for (int d = 0; d < 10; ++d) adj.p[d] = (const int*)d_in[4+d];
    const float* gc1_w0     = (const float*)d_in[14];
    const float* gc1_wself  = (const float*)d_in[15];
    const float* gc1_wneigh = (const float*)d_in[16];
    const float* gc1_b      = (const float*)d_in[17];
    const float* gc2_w0     = (const float*)d_in[18];
    const float* gc2_wself  = (const float*)d_in[19];
    const float* gc2_wneigh = (const float*)d_in[20];
    const float* gc2_b      = (const float*)d_in[21];
    const float* bn1g = (const float*)d_in[22]; const float* bn1b = (const float*)d_in[23];
    const float* bn1m = (const float*)d_in[24]; const float* bn1v = (const float*)d_in[25];
    const float* bn2g = (const float*)d_in[26]; const float* bn2b = (const float*)d_in[27];
    const float* bn2m = (const float*)d_in[28]; const float* bn2v = (const float*)d_in[29];
    const float* bn3g = (const float*)d_in[30]; const float* bn3b = (const float*)d_in[31];
    const float* bn3m = (const float*)d_in[32]; const float* bn3v = (const float*)d_in[33];
    const float* dense_w = (const float*)d_in[34];
    const float* dense_b = (const float*)d_in[35];
    const float* out_w   = (const float*)d_in[36];
    const float* out_b   = (const float*)d_in[37];

    // workspace (f16 units), single copies:
    f16_t* wsb = (f16_t*)d_ws;
    f16_t* xq    = wsb;                        //  6,291,456
    f16_t* NBX   = wsb + 6291456;              //  6,291,456 (blob NKB=3)
    f16_t* H1b   = wsb + 12582912;             // 16,777,216  (also H2; H3 starts here)
    f16_t* P1rm  = wsb + 29360128;             // 16,777,216
    f16_t* NB2b  = wsb + 46137344;             // 16,777,216 (blob NKB=8; later P2_bl)
    f16_t* H2b   = H1b;
    f16_t* P2bl  = NB2b;
    f16_t* H3b   = H1b;                        // 33,554,432 spans H1+P1rm
    f16_t* W1p   = wsb + 62914560;             //    540,672
    f16_t* W2p   = wsb + 63455232;             //  1,441,792
    f16_t* Wdp   = wsb + 64897024;             //    131,072
    f16_t* Wop   = wsb + 65028096;             //     32,768
    int*  counts = (int*)(wsb + 65060864);     // 2048 ints
    int*  slots  = counts + 2048;              // 65536 ints

    float* outp   = (float*)d_out;
    float* probs  = outp;            // 2048*24
    float* logits = outp + 49152;    // 2048*24
    float* fp     = outp + 98304;    // 2048*1024

    pack_cvt<<<11456, 256, 0, stream>>>(gc1_w0, gc1_wself, gc1_wneigh,
                                        gc2_w0, gc2_wself, gc2_wneigh,
                                        dense_w, out_w,
                                        W1p, W2p, Wdp, Wop, counts,
                                        atom, xq);

    // gc1: A0 = xq row-major (kb<3), A1 = NBX blob; direct, 1024 blocks
    nbsum_sc<<<3328, 256, 0, stream>>>(xq, NBX, adj, membership, counts, slots);
    gemm_gc<6,3,96,3,256,true><<<1024, 256, 0, stream>>>(
        xq, NBX, W1p, gc1_b, bn1g, bn1b, bn1m, bn1v, H1b);
    pool_k<false><<<(NATOMS*32)/256, 256, 0, stream>>>(H1b, P1rm, adj);

    // gc2: A0 = P1rm row-major (kb<8), A1 = NB2 blob; direct, 1024 blocks
    nbsum_k<<<(NATOMS*32)/256, 256, 0, stream>>>(P1rm, NB2b, adj);
    gemm_gc<16,8,256,8,256,true><<<1024, 256, 0, stream>>>(
        P1rm, NB2b, W2p, gc2_b, bn2g, bn2b, bn2m, bn2v, H2b);
    pool_k<true><<<(NATOMS*32)/256, 256, 0, stream>>>(H2b, P2bl, adj);

    // dense: direct blob->reg GEMM, reg-dbuf prefetch, XCD-grouped; 2048 x 256
    gemm_dir<<<2048, 256, 0, stream>>>(
        P2bl, Wdp, dense_b, bn3g, bn3b, bn3m, bn3v, H3b);

    // segment reduce + tanh -> fp (fp32, in d_out); 4 waves/segment
    reduce_k<<<2048, 256, 0, stream>>>(H3b, slots, fp);

    // readout
    final_mfma<<<128, 64, 0, stream>>>(fp, Wop, out_b, probs, logits);
}